// Round 1
// baseline (1399.423 us; speedup 1.0000x reference)
//
#include <hip/hip_runtime.h>
#include <hip/hip_bf16.h>
#include <math.h>

__device__ __forceinline__ float sigmoidf_(float x){ return 1.f/(1.f + expf(-x)); }

// ---------------- build x = [embed[dec_in], attn_hidden] : [64,1300] ----------------
__global__ void k_build_x(const int* __restrict__ dec_in,
                          const float* __restrict__ attn_hidden,
                          const float* __restrict__ embed,
                          float* __restrict__ x)
{
    int i = blockIdx.x*256 + threadIdx.x;
    if (i >= 64*1300) return;
    int b = i / 1300, k = i % 1300;
    float v;
    if (k < 300) v = embed[(long)dec_in[b]*300 + k];
    else         v = attn_hidden[b*1000 + (k-300)];
    x[i] = v;
}

// ---------------- C[64,N] = A[64,K] @ W[N,K]^T + bias  (NT: dot over contiguous k) ----
// lanes = batch. A staged transposed in LDS (conflict-free). W via wave-uniform loads.
template<int TJ>
__global__ void k_gemm_nt(const float* __restrict__ A,
                          const float* __restrict__ W,
                          const float* __restrict__ bias,
                          float* __restrict__ C,
                          int K, int N,
                          long dsA, long dsW, long dsB, long dsC)
{
    A    += (long)blockIdx.y * dsA;
    W    += (long)blockIdx.y * dsW;
    bias += (long)blockIdx.y * dsB;
    C    += (long)blockIdx.y * dsC;
    const int lane = threadIdx.x & 63;
    const int wave = threadIdx.x >> 6;
    const int g0 = __builtin_amdgcn_readfirstlane((blockIdx.x*4 + wave)*TJ);
    __shared__ float As[128][65];   // As[k][b]
    float acc[TJ];
#pragma unroll
    for (int j=0;j<TJ;j++) acc[j]=0.f;
    for (int kc = 0; kc < K; kc += 128) {
        int kchunk = min(128, K - kc);
        __syncthreads();
        for (int idx = threadIdx.x; idx < 64*128; idx += 256) {
            int col = idx & 127, row = idx >> 7;
            As[col][row] = (col < kchunk) ? A[(long)row*K + kc + col] : 0.f;
        }
        __syncthreads();
        const float* Wg = W + (long)g0*K + kc;
        if (g0 + TJ <= N) {
            for (int kk = 0; kk + 4 <= kchunk; kk += 4) {
                float a0 = As[kk][lane], a1 = As[kk+1][lane];
                float a2 = As[kk+2][lane], a3 = As[kk+3][lane];
#pragma unroll
                for (int j=0;j<TJ;j++) {
                    const float4 w = *(const float4*)(Wg + (long)j*K + kk);
                    acc[j] = fmaf(a0,w.x, fmaf(a1,w.y, fmaf(a2,w.z, fmaf(a3,w.w, acc[j]))));
                }
            }
        } else if (g0 < N) {
            int jn = N - g0;
            for (int kk = 0; kk + 4 <= kchunk; kk += 4) {
                float a0 = As[kk][lane], a1 = As[kk+1][lane];
                float a2 = As[kk+2][lane], a3 = As[kk+3][lane];
#pragma unroll
                for (int j=0;j<TJ;j++) {
                    if (j < jn) {
                        const float4 w = *(const float4*)(Wg + (long)j*K + kk);
                        acc[j] = fmaf(a0,w.x, fmaf(a1,w.y, fmaf(a2,w.z, fmaf(a3,w.w, acc[j]))));
                    }
                }
            }
        }
    }
#pragma unroll
    for (int j=0;j<TJ;j++) {
        if (g0 + j < N) C[(long)lane*N + g0 + j] = acc[j] + bias[g0+j];
    }
}

// ---------------- C[64,N] = act(A[64,K] @ W[K,N] + bias)  (NN) ------------------------
template<int TJ, int ACT>
__global__ void k_gemm_nn(const float* __restrict__ A,
                          const float* __restrict__ W,
                          const float* __restrict__ bias,
                          float* __restrict__ C,
                          int K, int N)
{
    const int lane = threadIdx.x & 63;
    const int wave = threadIdx.x >> 6;
    const int j0 = __builtin_amdgcn_readfirstlane((blockIdx.x*4 + wave)*TJ);
    __shared__ float As[128][65];   // As[h][b]
    float acc[TJ];
#pragma unroll
    for (int j=0;j<TJ;j++) acc[j]=0.f;
    for (int hc = 0; hc < K; hc += 128) {
        int hchunk = min(128, K - hc);
        __syncthreads();
        for (int idx = threadIdx.x; idx < 64*128; idx += 256) {
            int col = idx & 127, row = idx >> 7;
            As[col][row] = (col < hchunk) ? A[(long)row*K + hc + col] : 0.f;
        }
        __syncthreads();
        const float* Wc = W + (long)hc*N + j0;
        if (j0 + TJ <= N) {
            for (int hh = 0; hh < hchunk; hh++) {
                float a = As[hh][lane];
                const float* Wr = Wc + (long)hh*N;
#pragma unroll
                for (int j=0;j<TJ;j++) acc[j] = fmaf(a, Wr[j], acc[j]);
            }
        } else if (j0 < N) {
            int jn = N - j0;
            for (int hh = 0; hh < hchunk; hh++) {
                float a = As[hh][lane];
                const float* Wr = Wc + (long)hh*N;
#pragma unroll
                for (int j=0;j<TJ;j++) if (j < jn) acc[j] = fmaf(a, Wr[j], acc[j]);
            }
        }
    }
#pragma unroll
    for (int j=0;j<TJ;j++) {
        if (j0 + j < N) {
            float v = acc[j] + bias[j0+j];
            if (ACT) v = tanhf(v);
            C[(long)lane*N + j0 + j] = v;
        }
    }
}

// ---------------- GRU gate math (both directions via blockIdx.y) ----------------------
__global__ void k_gru_gates(const float* __restrict__ gi,
                            const float* __restrict__ gh,
                            const float* __restrict__ hprev,
                            float* __restrict__ out)
{
    int d = blockIdx.y;
    int i = blockIdx.x*256 + threadIdx.x;
    if (i >= 64*500) return;
    int b = i / 500, q = i % 500;
    const float* GI = gi + (long)d*96000 + (long)b*1500;
    const float* GH = gh + (long)d*96000 + (long)b*1500;
    float hp = hprev[(long)d*32000 + i];
    float r = sigmoidf_(GI[q]     + GH[q]);
    float z = sigmoidf_(GI[500+q] + GH[500+q]);
    float n = tanhf(GI[1000+q] + r*GH[1000+q]);
    out[(long)b*1000 + d*500 + q] = (1.f - z)*n + z*hp;
}

// ---------------- pt / window bounds --------------------------------------------------
__global__ void k_pt(const float* __restrict__ tmp,   // [64,1000] = tanh(ht@Wp+b)
                     const float* __restrict__ Vp_w,
                     const float* __restrict__ Vp_b,
                     const int* __restrict__ lengths,
                     int* __restrict__ p01)
{
    int b = blockIdx.x;
    float ps = 0.f;
    for (int j = threadIdx.x; j < 1000; j += 256) ps += tmp[b*1000 + j] * Vp_w[j];
    for (int off = 32; off; off >>= 1) ps += __shfl_down(ps, off);
    __shared__ float red[4];
    int lane = threadIdx.x & 63, wave = threadIdx.x >> 6;
    if (lane == 0) red[wave] = ps;
    __syncthreads();
    if (threadIdx.x == 0) {
        float tot = red[0]+red[1]+red[2]+red[3];
        float s = 1.f/(1.f + expf(-(tot + Vp_b[0])));
        int len = lengths[b];
        int pt = (int)((float)len * s);           // trunc, matches astype(int32)
        int P0 = min(len - 5, max(0, pt - 5));
        int P1 = min(len, pt + 6);
        p01[2*b] = P0; p01[2*b+1] = P1;
    }
}

// ---------------- windowed attention + build cat=[c, ht] ------------------------------
__global__ void k_attn(const float* __restrict__ enc,
                       const float* __restrict__ ht,
                       const int* __restrict__ p01,
                       float* __restrict__ cat)
{
    int b = blockIdx.x;
    __shared__ float hts[1000];
    __shared__ float hs[11][1000];
    __shared__ float aa[16];
    int p0 = p01[2*b], p1 = p01[2*b+1];
    for (int h = threadIdx.x; h < 1000; h += 256) hts[h] = ht[b*1000 + h];
    for (int k = 0; k < 11; k++) {
        int row = min(p0 + k, 1023);
        const float* er = enc + ((long)b*1024 + row)*1000;
        for (int h = threadIdx.x; h < 1000; h += 256) hs[k][h] = er[h];
    }
    __syncthreads();
    int lane = threadIdx.x & 63, wave = threadIdx.x >> 6;
    for (int k = wave; k < 11; k += 4) {
        float ps = 0.f;
        for (int h = lane; h < 1000; h += 64) ps += hts[h]*hs[k][h];
        for (int off = 32; off; off >>= 1) ps += __shfl_down(ps, off);
        if (lane == 0) aa[k] = ps;
    }
    __syncthreads();
    if (threadIdx.x == 0) {
        int nv = min(p1 - p0, 11);                // >=1 always
        float m = -1e30f;
        for (int k = 0; k < nv; k++) m = fmaxf(m, aa[k]);
        float ssum = 0.f;
        for (int k = 0; k < 11; k++) { float e = (k < nv) ? expf(aa[k]-m) : 0.f; aa[k] = e; ssum += e; }
        float inv = 1.f/ssum;
        for (int k = 0; k < 11; k++) aa[k] *= inv;
    }
    __syncthreads();
    for (int h = threadIdx.x; h < 1000; h += 256) {
        float c = 0.f;
#pragma unroll
        for (int k = 0; k < 11; k++) c += aa[k]*hs[k][h];
        cat[(long)b*2000 + h]        = c;
        cat[(long)b*2000 + 1000 + h] = hts[h];
    }
}

// ---------------- log_softmax: partial online (m,s) -> merge -> subtract --------------
__global__ void k_lse_part(const float* __restrict__ y, float* __restrict__ part)
{
    const int V = 50257;
    int b = blockIdx.x >> 3, p = blockIdx.x & 7;
    const int Vc = (V + 7)/8;
    int start = p*Vc, end = min(V, start + Vc);
    float m = -1e30f, s = 0.f;
    for (int j = start + threadIdx.x; j < end; j += 256) {
        float v = y[(long)b*V + j];
        if (v > m) { s = s*expf(m - v) + 1.f; m = v; }
        else       { s += expf(v - m); }
    }
    __shared__ float ms[256], ss[256];
    ms[threadIdx.x] = m; ss[threadIdx.x] = s;
    __syncthreads();
    for (int st = 128; st; st >>= 1) {
        if (threadIdx.x < st) {
            float m1 = ms[threadIdx.x], s1 = ss[threadIdx.x];
            float m2 = ms[threadIdx.x+st], s2 = ss[threadIdx.x+st];
            float M = fmaxf(m1, m2);
            ms[threadIdx.x] = M;
            ss[threadIdx.x] = s1*expf(m1-M) + s2*expf(m2-M);
        }
        __syncthreads();
    }
    if (threadIdx.x == 0) { part[2*blockIdx.x] = ms[0]; part[2*blockIdx.x+1] = ss[0]; }
}

__global__ void k_lse_merge(const float* __restrict__ part, float* __restrict__ lse)
{
    int b = threadIdx.x;
    if (b >= 64) return;
    float M = -1e30f, S = 0.f;
    for (int p = 0; p < 8; p++) {
        float m2 = part[2*(b*8+p)], s2 = part[2*(b*8+p)+1];
        float Mn = fmaxf(M, m2);
        S = S*expf(M - Mn) + s2*expf(m2 - Mn);
        M = Mn;
    }
    lse[b] = M + logf(S);
}

__global__ void k_sub(float* __restrict__ y, const float* __restrict__ lse)
{
    const int V = 50257;
    int b = blockIdx.y;
    int j = blockIdx.x*256 + threadIdx.x;
    if (j < V) y[(long)b*V + j] -= lse[b];
}

// =====================================================================================
extern "C" void kernel_launch(void* const* d_in, const int* in_sizes, int n_in,
                              void* d_out, int out_size, void* d_ws, size_t ws_size,
                              hipStream_t stream)
{
    const int*   dec_in  = (const int*)  d_in[0];
    const float* attn_h  = (const float*)d_in[1];
    const float* enc     = (const float*)d_in[2];
    // d_in[3] = mask0 (unused: m_w == valid within the window, proven from lengths)
    const int*   lengths = (const int*)  d_in[4];
    const float* h0      = (const float*)d_in[5];
    const float* embed   = (const float*)d_in[6];
    const float* w_ih0   = (const float*)d_in[7];
    const float* w_hh0   = (const float*)d_in[8];
    const float* b_ih0   = (const float*)d_in[9];
    const float* b_hh0   = (const float*)d_in[10];
    const float* w_ih1   = (const float*)d_in[11];
    const float* w_hh1   = (const float*)d_in[12];
    const float* b_ih1   = (const float*)d_in[13];
    const float* b_hh1   = (const float*)d_in[14];
    const float* Wp_w    = (const float*)d_in[15];
    const float* Wp_b    = (const float*)d_in[16];
    const float* Vp_w    = (const float*)d_in[17];
    const float* Vp_b    = (const float*)d_in[18];
    const float* Wc_w    = (const float*)d_in[19];
    const float* Wc_b    = (const float*)d_in[20];
    const float* out_w   = (const float*)d_in[21];
    const float* out_b   = (const float*)d_in[22];
    float* y = (float*)d_out;

    float* ws    = (float*)d_ws;
    float* x     = ws;             // 83200   [64,1300]
    float* gi    = ws + 83200;     // 192000  [2,64,1500]
    float* gh    = ws + 275200;    // 192000
    float* x1    = ws + 467200;    // 64000   [64,1000]
    float* ht    = ws + 531200;    // 64000
    float* tmp   = ws + 595200;    // 64000
    float* cat   = ws + 659200;    // 128000  [64,2000]
    float* hattn = ws + 787200;    // 64000
    float* part  = ws + 851200;    // 1024
    float* lse   = ws + 852224;    // 64
    int*   p01   = (int*)(ws + 852288); // 128 ints

    dim3 B256(256);

    k_build_x<<<dim3((64*1300 + 255)/256), B256, 0, stream>>>(dec_in, attn_h, embed, x);

    // GRU layer 0 (input = x, K=1300; hidden K=500), both directions via grid.y
    k_gemm_nt<4><<<dim3(94,2), B256, 0, stream>>>(x,  w_ih0, b_ih0, gi, 1300, 1500, 0L,     1950000L, 1500L, 96000L);
    k_gemm_nt<4><<<dim3(94,2), B256, 0, stream>>>(h0, w_hh0, b_hh0, gh,  500, 1500, 32000L,  750000L, 1500L, 96000L);
    k_gru_gates<<<dim3(125,2), B256, 0, stream>>>(gi, gh, h0, x1);

    // GRU layer 1 (input = x1, K=1000)
    k_gemm_nt<4><<<dim3(94,2), B256, 0, stream>>>(x1,       w_ih1, b_ih1, gi, 1000, 1500, 0L,     1500000L, 1500L, 96000L);
    k_gemm_nt<4><<<dim3(94,2), B256, 0, stream>>>(h0+64000, w_hh1, b_hh1, gh,  500, 1500, 32000L,  750000L, 1500L, 96000L);
    k_gru_gates<<<dim3(125,2), B256, 0, stream>>>(gi, gh, h0+64000, ht);

    // predictive window position
    k_gemm_nn<4,1><<<dim3(63), B256, 0, stream>>>(ht, Wp_w, Wp_b, tmp, 1000, 1000);
    k_pt<<<dim3(64), B256, 0, stream>>>(tmp, Vp_w, Vp_b, lengths, p01);

    // local attention + concat
    k_attn<<<dim3(64), B256, 0, stream>>>(enc, ht, p01, cat);
    k_gemm_nn<4,1><<<dim3(63), B256, 0, stream>>>(cat, Wc_w, Wc_b, hattn, 2000, 1000);

    // output projection [64,50257] into d_out
    k_gemm_nn<16,0><<<dim3(786), B256, 0, stream>>>(hattn, out_w, out_b, y, 1000, 50257);

    // log_softmax in place
    k_lse_part<<<dim3(512), B256, 0, stream>>>(y, part);
    k_lse_merge<<<dim3(1), dim3(64), 0, stream>>>(part, lse);
    k_sub<<<dim3((50257+255)/256, 64), B256, 0, stream>>>(y, lse);
}

// Round 2
// 757.493 us; speedup vs baseline: 1.8474x; 1.8474x over previous
//
#include <hip/hip_runtime.h>
#include <hip/hip_bf16.h>
#include <math.h>

__device__ __forceinline__ float sigmoidf_(float x){ return 1.f/(1.f + expf(-x)); }

// ============ one-time transpose of the 4 GRU weight mats [N=1500][K] -> [K][1500] ====
__global__ void k_transpose_w(const float* __restrict__ w_ih0, const float* __restrict__ w_hh0,
                              const float* __restrict__ w_ih1, const float* __restrict__ w_hh1,
                              float* __restrict__ t_ih0, float* __restrict__ t_hh0,
                              float* __restrict__ t_ih1, float* __restrict__ t_hh1)
{
    int z = blockIdx.z; int which = z >> 1, dir = z & 1;
    const float* src; float* dst; int Kz;
    if      (which == 0) { src = w_ih0; dst = t_ih0; Kz = 1300; }
    else if (which == 1) { src = w_hh0; dst = t_hh0; Kz = 500;  }
    else if (which == 2) { src = w_ih1; dst = t_ih1; Kz = 1000; }
    else                 { src = w_hh1; dst = t_hh1; Kz = 500;  }
    src += (long)dir * 1500 * Kz;
    dst += (long)dir * 1500 * Kz;
    __shared__ float tile[32][33];
    int c0 = blockIdx.x * 32;   // k base
    int r0 = blockIdx.y * 32;   // n base
    for (int ry = threadIdx.y; ry < 32; ry += 8) {
        int r = r0 + ry, c = c0 + threadIdx.x;
        tile[ry][threadIdx.x] = (r < 1500 && c < Kz) ? src[(long)r * Kz + c] : 0.f;
    }
    __syncthreads();
    for (int ry = threadIdx.y; ry < 32; ry += 8) {
        int kk = c0 + ry, n = r0 + threadIdx.x;
        if (kk < Kz && n < 1500) dst[(long)kk * 1500 + n] = tile[threadIdx.x][ry];
    }
}

// ============ build xT [1300][64] and h0T [4][500][64] ================================
__global__ void k_prep(const int* __restrict__ dec_in, const float* __restrict__ attn_h,
                       const float* __restrict__ embed, const float* __restrict__ h0,
                       float* __restrict__ xT, float* __restrict__ h0T)
{
    int i = blockIdx.x * 256 + threadIdx.x;
    if (i < 64 * 1300) {
        int k = i >> 6, b = i & 63;
        xT[i] = (k < 300) ? embed[(long)dec_in[b] * 300 + k] : attn_h[b * 1000 + (k - 300)];
        return;
    }
    i -= 64 * 1300;
    if (i < 4 * 500 * 64) {
        int d = i / 32000, r = i % 32000, k = r >> 6, b = r & 63;
        h0T[d * 32000 + r] = h0[((long)d * 64 + b) * 500 + k];
    }
}

// ============ outer-product GEMM: P[s][d][64][N] = AT_chunk^T x W_chunk ===============
// lane = column n (coalesced W stream, vmcnt-pipelined); acc[64] over batch;
// A broadcast via wave-uniform s_load (all waves share the same K$-hot AT stream).
template<int KLEN, int BIAS>
__global__ __launch_bounds__(256) void k_nn(
    const float* __restrict__ AT, const float* __restrict__ W,
    const float* __restrict__ bias, float* __restrict__ out,
    int N, long sATd, long sWd)
{
    const int d = blockIdx.z;
    AT  += (long)d * sATd + (long)blockIdx.y * KLEN * 64;
    W   += (long)d * sWd  + (long)blockIdx.y * KLEN * N;
    out += ((long)blockIdx.y * gridDim.z + d) * ((long)64 * N);
    const int lane = threadIdx.x & 63;
    const int wave = threadIdx.x >> 6;
    const int n = (blockIdx.x * 4 + wave) * 64 + lane;
    const bool ok = n < N;
    const int nc = ok ? n : (N - 1);
    const float* wp = W + nc;

    float acc[64];
#pragma unroll
    for (int b = 0; b < 64; b++) acc[b] = 0.f;

    auto fma_blk = [&](int kk, float wreg) {
        const float* ak = AT + (long)kk * 64;
        float av[64];
#pragma unroll
        for (int b = 0; b < 64; b++) av[b] = ak[b];     // uniform -> s_load_dwordx16
#pragma unroll
        for (int b = 0; b < 64; b++) acc[b] = fmaf(av[b], wreg, acc[b]);
    };

    float w0 = wp[0];
    float w1 = wp[(long)1 * N];
    float w2 = wp[(long)2 * N];
    float w3 = wp[(long)3 * N];

    for (int k = 0; k < KLEN; k += 4) {
        const long o4 = (long)min(k + 4, KLEN - 1) * N;
        const long o5 = (long)min(k + 5, KLEN - 1) * N;
        const long o6 = (long)min(k + 6, KLEN - 1) * N;
        const long o7 = (long)min(k + 7, KLEN - 1) * N;
        float n0 = wp[o4], n1 = wp[o5], n2 = wp[o6], n3 = wp[o7];
        fma_blk(k + 0, w0);
        fma_blk(k + 1, w1);
        fma_blk(k + 2, w2);
        fma_blk(k + 3, w3);
        w0 = n0; w1 = n1; w2 = n2; w3 = n3;
    }

    const float bv = BIAS ? bias[nc] : 0.f;
#pragma unroll
    for (int b = 0; b < 64; b++) {
        if (ok) out[(long)b * N + n] = acc[b] + bv;
    }
}

// ============ GRU gate math: sum split-K partials + biases, gate nonlinearity =========
template<int LAYER>
__global__ void k_gates(const float* __restrict__ Pgi, const float* __restrict__ Pgh,
                        const float* __restrict__ h0,
                        const float* __restrict__ b_ih, const float* __restrict__ b_hh,
                        float* __restrict__ outT, float* __restrict__ ht, int SI)
{
    const int d = blockIdx.y;
    int i = blockIdx.x * 256 + threadIdx.x;
    if (i >= 32000) return;
    int b = i / 500, q = i % 500;
    long base = (long)b * 1500 + q;
    float g0 = b_ih[d * 1500 + q], g1 = b_ih[d * 1500 + 500 + q], g2 = b_ih[d * 1500 + 1000 + q];
    for (int s = 0; s < SI; s++) {
        const float* P = Pgi + ((long)(s * 2 + d)) * 96000 + base;
        g0 += P[0]; g1 += P[500]; g2 += P[1000];
    }
    float h0v = b_hh[d * 1500 + q], h1v = b_hh[d * 1500 + 500 + q], h2v = b_hh[d * 1500 + 1000 + q];
    for (int s = 0; s < 5; s++) {
        const float* P = Pgh + ((long)(s * 2 + d)) * 96000 + base;
        h0v += P[0]; h1v += P[500]; h2v += P[1000];
    }
    float hp = h0[((long)(LAYER * 2 + d) * 64 + b) * 500 + q];
    float r = sigmoidf_(g0 + h0v);
    float z = sigmoidf_(g1 + h1v);
    float nn = tanhf(g2 + r * h2v);
    float o = (1.f - z) * nn + z * hp;
    outT[(long)(d * 500 + q) * 64 + b] = o;
    if (LAYER == 1) ht[(long)b * 1000 + d * 500 + q] = o;
}

// ============ pt / window bounds (consumes Wp split-K partials) =======================
__global__ void k_pt(const float* __restrict__ Pwp, const float* __restrict__ Wp_b,
                     const float* __restrict__ Vp_w, const float* __restrict__ Vp_b,
                     const int* __restrict__ lengths, int* __restrict__ p01)
{
    int b = blockIdx.x;
    float ps = 0.f;
    for (int j = threadIdx.x; j < 1000; j += 256) {
        float v = Wp_b[j];
        for (int s = 0; s < 10; s++) v += Pwp[(long)s * 64000 + (long)b * 1000 + j];
        ps += tanhf(v) * Vp_w[j];
    }
    for (int off = 32; off; off >>= 1) ps += __shfl_down(ps, off);
    __shared__ float red[4];
    int lane = threadIdx.x & 63, wave = threadIdx.x >> 6;
    if (lane == 0) red[wave] = ps;
    __syncthreads();
    if (threadIdx.x == 0) {
        float tot = red[0] + red[1] + red[2] + red[3];
        float s = 1.f / (1.f + expf(-(tot + Vp_b[0])));
        int len = lengths[b];
        int pt = (int)((float)len * s);
        int P0 = min(len - 5, max(0, pt - 5));
        int P1 = min(len, pt + 6);
        p01[2 * b] = P0; p01[2 * b + 1] = P1;
    }
}

// ============ windowed attention; writes catT [2000][64] ==============================
__global__ void k_attn(const float* __restrict__ enc, const float* __restrict__ ht,
                       const int* __restrict__ p01, float* __restrict__ catT)
{
    int b = blockIdx.x;
    __shared__ float hts[1000];
    __shared__ float hs[11][1000];
    __shared__ float aa[16];
    int p0 = p01[2 * b], p1 = p01[2 * b + 1];
    for (int h = threadIdx.x; h < 1000; h += 256) hts[h] = ht[b * 1000 + h];
    for (int k = 0; k < 11; k++) {
        int row = min(p0 + k, 1023);
        const float* er = enc + ((long)b * 1024 + row) * 1000;
        for (int h = threadIdx.x; h < 1000; h += 256) hs[k][h] = er[h];
    }
    __syncthreads();
    int lane = threadIdx.x & 63, wave = threadIdx.x >> 6;
    for (int k = wave; k < 11; k += 4) {
        float ps = 0.f;
        for (int h = lane; h < 1000; h += 64) ps += hts[h] * hs[k][h];
        for (int off = 32; off; off >>= 1) ps += __shfl_down(ps, off);
        if (lane == 0) aa[k] = ps;
    }
    __syncthreads();
    if (threadIdx.x == 0) {
        int nv = min(p1 - p0, 11);
        float m = -1e30f;
        for (int k = 0; k < nv; k++) m = fmaxf(m, aa[k]);
        float ssum = 0.f;
        for (int k = 0; k < 11; k++) { float e = (k < nv) ? expf(aa[k] - m) : 0.f; aa[k] = e; ssum += e; }
        float inv = 1.f / ssum;
        for (int k = 0; k < 11; k++) aa[k] *= inv;
    }
    __syncthreads();
    for (int h = threadIdx.x; h < 1000; h += 256) {
        float c = 0.f;
#pragma unroll
        for (int k = 0; k < 11; k++) c += aa[k] * hs[k][h];
        catT[(long)h * 64 + b]          = c;
        catT[(long)(1000 + h) * 64 + b] = hts[h];
    }
}

// ============ combine Wc partials + tanh -> hattnT [1000][64] =========================
__global__ void k_hattn(const float* __restrict__ Phc, const float* __restrict__ Wc_b,
                        float* __restrict__ hattnT)
{
    int i = blockIdx.x * 256 + threadIdx.x;
    if (i >= 64000) return;
    int nidx = i >> 6, b = i & 63;
    float v = Wc_b[nidx];
    for (int s = 0; s < 20; s++) v += Phc[(long)s * 64000 + (long)b * 1000 + nidx];
    hattnT[i] = tanhf(v);
}

// ============ log_softmax =============================================================
__global__ void k_lse_part(const float* __restrict__ y, float* __restrict__ part)
{
    const int V = 50257;
    int b = blockIdx.x >> 3, p = blockIdx.x & 7;
    const int Vc = (V + 7) / 8;
    int start = p * Vc, end = min(V, start + Vc);
    float m = -1e30f, s = 0.f;
    for (int j = start + threadIdx.x; j < end; j += 256) {
        float v = y[(long)b * V + j];
        if (v > m) { s = s * expf(m - v) + 1.f; m = v; }
        else       { s += expf(v - m); }
    }
    __shared__ float ms[256], ss[256];
    ms[threadIdx.x] = m; ss[threadIdx.x] = s;
    __syncthreads();
    for (int st = 128; st; st >>= 1) {
        if (threadIdx.x < st) {
            float m1 = ms[threadIdx.x], s1 = ss[threadIdx.x];
            float m2 = ms[threadIdx.x + st], s2 = ss[threadIdx.x + st];
            float M = fmaxf(m1, m2);
            ms[threadIdx.x] = M;
            ss[threadIdx.x] = s1 * expf(m1 - M) + s2 * expf(m2 - M);
        }
        __syncthreads();
    }
    if (threadIdx.x == 0) { part[2 * blockIdx.x] = ms[0]; part[2 * blockIdx.x + 1] = ss[0]; }
}

__global__ void k_lse_merge(const float* __restrict__ part, float* __restrict__ lse)
{
    int b = threadIdx.x;
    if (b >= 64) return;
    float M = -1e30f, S = 0.f;
    for (int p = 0; p < 8; p++) {
        float m2 = part[2 * (b * 8 + p)], s2 = part[2 * (b * 8 + p) + 1];
        float Mn = fmaxf(M, m2);
        S = S * expf(M - Mn) + s2 * expf(m2 - Mn);
        M = Mn;
    }
    lse[b] = M + logf(S);
}

__global__ void k_sub(float* __restrict__ y, const float* __restrict__ lse)
{
    const int V = 50257;
    int b = blockIdx.y;
    int j = blockIdx.x * 256 + threadIdx.x;
    if (j < V) y[(long)b * V + j] -= lse[b];
}

// =====================================================================================
extern "C" void kernel_launch(void* const* d_in, const int* in_sizes, int n_in,
                              void* d_out, int out_size, void* d_ws, size_t ws_size,
                              hipStream_t stream)
{
    const int*   dec_in  = (const int*)  d_in[0];
    const float* attn_h  = (const float*)d_in[1];
    const float* enc     = (const float*)d_in[2];
    // d_in[3] = mask0 (unused: m_w == valid within the window)
    const int*   lengths = (const int*)  d_in[4];
    const float* h0      = (const float*)d_in[5];
    const float* embed   = (const float*)d_in[6];
    const float* w_ih0   = (const float*)d_in[7];
    const float* w_hh0   = (const float*)d_in[8];
    const float* b_ih0   = (const float*)d_in[9];
    const float* b_hh0   = (const float*)d_in[10];
    const float* w_ih1   = (const float*)d_in[11];
    const float* w_hh1   = (const float*)d_in[12];
    const float* b_ih1   = (const float*)d_in[13];
    const float* b_hh1   = (const float*)d_in[14];
    const float* Wp_w    = (const float*)d_in[15];
    const float* Wp_b    = (const float*)d_in[16];
    const float* Vp_w    = (const float*)d_in[17];
    const float* Vp_b    = (const float*)d_in[18];
    const float* Wc_w    = (const float*)d_in[19];
    const float* Wc_b    = (const float*)d_in[20];
    const float* out_w   = (const float*)d_in[21];
    const float* out_b   = (const float*)d_in[22];
    float* y = (float*)d_out;

    float* ws = (float*)d_ws;
    float* wt_ih0 = ws + 0;         // 3,900,000
    float* wt_hh0 = ws + 3900000;   // 1,500,000
    float* wt_ih1 = ws + 5400000;   // 3,000,000
    float* wt_hh1 = ws + 8400000;   // 1,500,000
    float* xT     = ws + 9900000;   // 83,200
    float* h0T    = ws + 9983200;   // 128,000
    float* Pgi    = ws + 10111200;  // 2,496,000 (13*2*96000; reused for L1)
    float* Pgh    = ws + 12607200;  // 960,000
    float* x1T    = ws + 13567200;  // 64,000
    float* ht     = ws + 13631200;  // 64,000
    float* htT    = ws + 13695200;  // 64,000
    float* Pwp    = ws + 13759200;  // 640,000
    float* catT   = ws + 14399200;  // 128,000
    float* Phc    = ws + 14527200;  // 1,280,000
    float* hattnT = ws + 15807200;  // 64,000
    float* part   = ws + 15871200;  // 1,024
    float* lse    = ws + 15872224;  // 64
    int*   p01    = (int*)(ws + 15872288);

    dim3 B256(256);

    k_transpose_w<<<dim3(41, 47, 8), dim3(32, 8), 0, stream>>>(
        w_ih0, w_hh0, w_ih1, w_hh1, wt_ih0, wt_hh0, wt_ih1, wt_hh1);
    k_prep<<<dim3(825), B256, 0, stream>>>(dec_in, attn_h, embed, h0, xT, h0T);

    // GRU layer 0
    k_nn<100, 0><<<dim3(6, 13, 2), B256, 0, stream>>>(xT,  wt_ih0, nullptr, Pgi, 1500, 0L,     1950000L);
    k_nn<100, 0><<<dim3(6, 5, 2),  B256, 0, stream>>>(h0T, wt_hh0, nullptr, Pgh, 1500, 32000L, 750000L);
    k_gates<0><<<dim3(125, 2), B256, 0, stream>>>(Pgi, Pgh, h0, b_ih0, b_hh0, x1T, x1T, 13);

    // GRU layer 1
    k_nn<100, 0><<<dim3(6, 10, 2), B256, 0, stream>>>(x1T,         wt_ih1, nullptr, Pgi, 1500, 0L,     1500000L);
    k_nn<100, 0><<<dim3(6, 5, 2),  B256, 0, stream>>>(h0T + 64000, wt_hh1, nullptr, Pgh, 1500, 32000L, 750000L);
    k_gates<1><<<dim3(125, 2), B256, 0, stream>>>(Pgi, Pgh, h0, b_ih1, b_hh1, htT, ht, 10);

    // predictive window
    k_nn<100, 0><<<dim3(4, 10, 1), B256, 0, stream>>>(htT, Wp_w, nullptr, Pwp, 1000, 0L, 0L);
    k_pt<<<dim3(64), B256, 0, stream>>>(Pwp, Wp_b, Vp_w, Vp_b, lengths, p01);

    // local attention + Wc
    k_attn<<<dim3(64), B256, 0, stream>>>(enc, ht, p01, catT);
    k_nn<100, 0><<<dim3(4, 20, 1), B256, 0, stream>>>(catT, Wc_w, nullptr, Phc, 1000, 0L, 0L);
    k_hattn<<<dim3(250), B256, 0, stream>>>(Phc, Wc_b, hattnT);

    // output projection
    k_nn<1000, 1><<<dim3(197, 1, 1), B256, 0, stream>>>(hattnT, out_w, out_b, y, 50257, 0L, 0L);

    // log_softmax in place
    k_lse_part<<<dim3(512), B256, 0, stream>>>(y, part);
    k_lse_merge<<<dim3(1), dim3(64), 0, stream>>>(part, lse);
    k_sub<<<dim3(197, 64), B256, 0, stream>>>(y, lse);
}

// Round 5
// 236.344 us; speedup vs baseline: 5.9211x; 3.2050x over previous
//
#include <hip/hip_runtime.h>
#include <hip/hip_bf16.h>
#include <math.h>

typedef __attribute__((ext_vector_type(8))) short bf16x8;
typedef __attribute__((ext_vector_type(4))) float f32x4;

__device__ __forceinline__ float sigmoidf_(float x){ return 1.f/(1.f + expf(-x)); }
__device__ __forceinline__ short f2bf(float x){
    union { __hip_bfloat16 h; short s; } u; u.h = __float2bfloat16(x); return u.s;
}
__device__ __forceinline__ float bf2f(short s){
    union { unsigned u; float f; } v; v.u = ((unsigned)(unsigned short)s) << 16; return v.f;
}

// =====================================================================================
// Single-precision (bf16) MFMA GEMM core. C[64][N] = A[64][Kp]_bf16 @ B (+bias).
// TRANS=1: W is [N][K] row-major; TRANS=0: W is [K][N] row-major.
// Frag layout (guide §3, m89-verified): A/B lane l: 8 consecutive k=(l>>4)*8+j,
// row/col = l&15. C/D: col=l&15, row=(l>>4)*4+reg.
// =====================================================================================
template<int TRANS, int BIAS>
__device__ __forceinline__ void mm_core(
    const short* __restrict__ Abf, const float* __restrict__ W,
    const float* __restrict__ bias, float* __restrict__ outP,
    int K, int Kp, int N, int ks0, int ks1, int nblk)
{
    const int lane = threadIdx.x & 63;
    const int wave = threadIdx.x >> 6;
    const int l16  = lane & 15;
    const int lg   = lane >> 4;
    const int n    = nblk*64 + wave*16 + l16;
    const int nc   = min(n, N-1);

    f32x4 acc[4];
#pragma unroll
    for (int mt = 0; mt < 4; mt++) acc[mt] = f32x4{0.f,0.f,0.f,0.f};

    for (int ks = ks0; ks < ks1; ks++) {
        const int kl = ks*32 + lg*8;
        const short* ap = Abf + (long)l16*Kp + kl;
        bf16x8 a0 = *(const bf16x8*)(ap);
        bf16x8 a1 = *(const bf16x8*)(ap + (long)16*Kp);
        bf16x8 a2 = *(const bf16x8*)(ap + (long)32*Kp);
        bf16x8 a3 = *(const bf16x8*)(ap + (long)48*Kp);
        float wv[8];
        if (TRANS) {
            const float* wr = W + (long)nc*K;
            if (kl + 8 <= K) {
                float4 f0 = *(const float4*)(wr + kl);
                float4 f1 = *(const float4*)(wr + kl + 4);
                wv[0]=f0.x; wv[1]=f0.y; wv[2]=f0.z; wv[3]=f0.w;
                wv[4]=f1.x; wv[5]=f1.y; wv[6]=f1.z; wv[7]=f1.w;
            } else {
#pragma unroll
                for (int j=0;j<8;j++) wv[j] = wr[min(kl+j, K-1)];
            }
        } else {
            const float* wk = W + (long)kl*(long)N + nc;
            if (kl + 8 <= K) {
#pragma unroll
                for (int j=0;j<8;j++) wv[j] = wk[(long)j*N];
            } else {
#pragma unroll
                for (int j=0;j<8;j++) wv[j] = (kl+j < K) ? wk[(long)j*N] : 0.f;
            }
        }
        bf16x8 b;
#pragma unroll
        for (int j=0;j<8;j++) b[j] = f2bf(wv[j]);

        acc[0] = __builtin_amdgcn_mfma_f32_16x16x32_bf16(a0, b, acc[0], 0, 0, 0);
        acc[1] = __builtin_amdgcn_mfma_f32_16x16x32_bf16(a1, b, acc[1], 0, 0, 0);
        acc[2] = __builtin_amdgcn_mfma_f32_16x16x32_bf16(a2, b, acc[2], 0, 0, 0);
        acc[3] = __builtin_amdgcn_mfma_f32_16x16x32_bf16(a3, b, acc[3], 0, 0, 0);
    }

    if (n < N) {
        const float bv = BIAS ? bias[n] : 0.f;
#pragma unroll
        for (int mt = 0; mt < 4; mt++) {
#pragma unroll
            for (int q = 0; q < 4; q++) {
                int row = mt*16 + lg*4 + q;
                outP[(long)row*N + n] = acc[mt][q] + bv;
            }
        }
    }
}

// =====================================================================================
// Split-precision (hi+lo bf16, 4 MFMA products) core — fp32-class accuracy.
// Used for every GEMM feeding the discrete pt decision.
// =====================================================================================
template<int TRANS>
__device__ __forceinline__ void mm_core4(
    const short* __restrict__ Ahi, const short* __restrict__ Alo,
    const float* __restrict__ W, float* __restrict__ outP,
    int K, int Kp, int N, int ks0, int ks1, int nblk)
{
    const int lane = threadIdx.x & 63;
    const int wave = threadIdx.x >> 6;
    const int l16  = lane & 15;
    const int lg   = lane >> 4;
    const int n    = nblk*64 + wave*16 + l16;
    const int nc   = min(n, N-1);

    f32x4 acc[4];
#pragma unroll
    for (int mt = 0; mt < 4; mt++) acc[mt] = f32x4{0.f,0.f,0.f,0.f};

    for (int ks = ks0; ks < ks1; ks++) {
        const int kl = ks*32 + lg*8;
        const long o0 = (long)l16*Kp + kl;
        bf16x8 ah0 = *(const bf16x8*)(Ahi + o0);
        bf16x8 ah1 = *(const bf16x8*)(Ahi + o0 + (long)16*Kp);
        bf16x8 ah2 = *(const bf16x8*)(Ahi + o0 + (long)32*Kp);
        bf16x8 ah3 = *(const bf16x8*)(Ahi + o0 + (long)48*Kp);
        bf16x8 al0 = *(const bf16x8*)(Alo + o0);
        bf16x8 al1 = *(const bf16x8*)(Alo + o0 + (long)16*Kp);
        bf16x8 al2 = *(const bf16x8*)(Alo + o0 + (long)32*Kp);
        bf16x8 al3 = *(const bf16x8*)(Alo + o0 + (long)48*Kp);
        float wv[8];
        if (TRANS) {
            const float* wr = W + (long)nc*K;
            if (kl + 8 <= K) {
                float4 f0 = *(const float4*)(wr + kl);
                float4 f1 = *(const float4*)(wr + kl + 4);
                wv[0]=f0.x; wv[1]=f0.y; wv[2]=f0.z; wv[3]=f0.w;
                wv[4]=f1.x; wv[5]=f1.y; wv[6]=f1.z; wv[7]=f1.w;
            } else {
#pragma unroll
                for (int j=0;j<8;j++) wv[j] = wr[min(kl+j, K-1)];
            }
        } else {
            const float* wk = W + (long)kl*(long)N + nc;
            if (kl + 8 <= K) {
#pragma unroll
                for (int j=0;j<8;j++) wv[j] = wk[(long)j*N];
            } else {
#pragma unroll
                for (int j=0;j<8;j++) wv[j] = (kl+j < K) ? wk[(long)j*N] : 0.f;
            }
        }
        bf16x8 bh, bl;
#pragma unroll
        for (int j=0;j<8;j++) {
            short h = f2bf(wv[j]);
            bh[j] = h;
            bl[j] = f2bf(wv[j] - bf2f(h));
        }
        acc[0] = __builtin_amdgcn_mfma_f32_16x16x32_bf16(ah0, bh, acc[0], 0, 0, 0);
        acc[1] = __builtin_amdgcn_mfma_f32_16x16x32_bf16(ah1, bh, acc[1], 0, 0, 0);
        acc[2] = __builtin_amdgcn_mfma_f32_16x16x32_bf16(ah2, bh, acc[2], 0, 0, 0);
        acc[3] = __builtin_amdgcn_mfma_f32_16x16x32_bf16(ah3, bh, acc[3], 0, 0, 0);
        acc[0] = __builtin_amdgcn_mfma_f32_16x16x32_bf16(ah0, bl, acc[0], 0, 0, 0);
        acc[1] = __builtin_amdgcn_mfma_f32_16x16x32_bf16(ah1, bl, acc[1], 0, 0, 0);
        acc[2] = __builtin_amdgcn_mfma_f32_16x16x32_bf16(ah2, bl, acc[2], 0, 0, 0);
        acc[3] = __builtin_amdgcn_mfma_f32_16x16x32_bf16(ah3, bl, acc[3], 0, 0, 0);
        acc[0] = __builtin_amdgcn_mfma_f32_16x16x32_bf16(al0, bh, acc[0], 0, 0, 0);
        acc[1] = __builtin_amdgcn_mfma_f32_16x16x32_bf16(al1, bh, acc[1], 0, 0, 0);
        acc[2] = __builtin_amdgcn_mfma_f32_16x16x32_bf16(al2, bh, acc[2], 0, 0, 0);
        acc[3] = __builtin_amdgcn_mfma_f32_16x16x32_bf16(al3, bh, acc[3], 0, 0, 0);
        acc[0] = __builtin_amdgcn_mfma_f32_16x16x32_bf16(al0, bl, acc[0], 0, 0, 0);
        acc[1] = __builtin_amdgcn_mfma_f32_16x16x32_bf16(al1, bl, acc[1], 0, 0, 0);
        acc[2] = __builtin_amdgcn_mfma_f32_16x16x32_bf16(al2, bl, acc[2], 0, 0, 0);
        acc[3] = __builtin_amdgcn_mfma_f32_16x16x32_bf16(al3, bl, acc[3], 0, 0, 0);
    }

    if (n < N) {
#pragma unroll
        for (int mt = 0; mt < 4; mt++) {
#pragma unroll
            for (int q = 0; q < 4; q++) {
                int row = mt*16 + lg*4 + q;
                outP[(long)row*N + n] = acc[mt][q];
            }
        }
    }
}

// ============ prep: hi/lo A matrices, zero tails =====================================
__global__ void k_prep(const int* __restrict__ dec_in, const float* __restrict__ attn_h,
                       const float* __restrict__ embed, const float* __restrict__ h0,
                       short* __restrict__ xhi, short* __restrict__ xlo,
                       short* __restrict__ h0hi, short* __restrict__ h0lo,
                       short* __restrict__ x1hi, short* __restrict__ x1lo,
                       short* __restrict__ hthi, short* __restrict__ htlo,
                       short* __restrict__ habf, short* __restrict__ catbf)
{
    int i = blockIdx.x*256 + threadIdx.x;
    if (i < 64*1312) {                       // x [64][1312]
        int b = i / 1312, k = i % 1312;
        float v = 0.f;
        if (k < 300)       v = embed[(long)dec_in[b]*300 + k];
        else if (k < 1300) v = attn_h[b*1000 + (k-300)];
        short h = f2bf(v);
        xhi[i] = h; xlo[i] = f2bf(v - bf2f(h));
        return;
    }
    i -= 64*1312;
    if (i < 4*64*512) {                      // h0 [4][64][512]
        int d = i >> 15, r = i & 32767, b = r >> 9, k = r & 511;
        float v = (k < 500) ? h0[((long)d*64 + b)*500 + k] : 0.f;
        short h = f2bf(v);
        h0hi[i] = h; h0lo[i] = f2bf(v - bf2f(h));
        return;
    }
    i -= 4*64*512;
    if (i < 1536) {                          // x1/ht hi+lo tails
        int b = i/24; long o = (long)b*1024 + 1000 + i%24;
        x1hi[o]=0; x1lo[o]=0; hthi[o]=0; htlo[o]=0; return;
    }
    i -= 1536;
    if (i < 1536) { int b = i/24; habf[(long)b*1024 + 1000 + i%24] = 0; return; }
    i -= 1536;
    if (i < 3072) { int b = i/48; catbf[(long)b*2048 + 2000 + i%48] = 0; return; }
}

// ============ fused GRU GEMM (split-precision): z<2 ih dir z ; z>=2 hh dir z-2 ========
template<int LAYER>
__global__ __launch_bounds__(256) void k_gru_mm(
    const short* __restrict__ Aih_hi, const short* __restrict__ Aih_lo,
    const short* __restrict__ h0hi,   const short* __restrict__ h0lo,
    const float* __restrict__ w_ih, const float* __restrict__ w_hh,
    float* __restrict__ Pgi, float* __restrict__ Pgh,
    int Kih, int Kpih, int Sih, int stepsih, int Shh, int stepshh)
{
    int z = blockIdx.z, s = blockIdx.y, nblk = blockIdx.x;
    if (z < 2) {
        if (s >= Sih) return;
        int nsteps = Kpih >> 5;
        int ks0 = s*stepsih, ks1 = min(nsteps, ks0 + stepsih);
        if (ks0 >= ks1) return;
        const float* W = w_ih + (long)z*1500*Kih;
        float* outP = Pgi + (long)(z*Sih + s)*96000;
        mm_core4<1>(Aih_hi, Aih_lo, W, outP, Kih, Kpih, 1500, ks0, ks1, nblk);
    } else {
        int d = z - 2;
        if (s >= Shh) return;
        int ks0 = s*stepshh, ks1 = min(16, ks0 + stepshh);
        if (ks0 >= ks1) return;
        const float* W = w_hh + (long)d*1500*500;
        float* outP = Pgh + (long)(d*Shh + s)*96000;
        const long ao = (long)(LAYER*2 + d)*64*512;
        mm_core4<1>(h0hi + ao, h0lo + ao, W, outP, 500, 512, 1500, ks0, ks1, nblk);
    }
}

// ============ NN split-K GEMM, split-precision (Wp) ==================================
__global__ __launch_bounds__(256) void k_nn_split4(
    const short* __restrict__ Ahi, const short* __restrict__ Alo,
    const float* __restrict__ W,
    float* __restrict__ P, int K, int Kp, int N, int steps)
{
    int s = blockIdx.y;
    int ks0 = s*steps, ks1 = min(Kp >> 5, ks0 + steps);
    if (ks0 >= ks1) return;
    mm_core4<0>(Ahi, Alo, W, P + (long)s*64*N, K, Kp, N, ks0, ks1, blockIdx.x);
}

// ============ NN split-K GEMM, single precision (Wc) =================================
__global__ __launch_bounds__(256) void k_nn_split(
    const short* __restrict__ Abf, const float* __restrict__ W,
    float* __restrict__ P, int K, int Kp, int N, int steps)
{
    int s = blockIdx.y;
    int ks0 = s*steps, ks1 = min(Kp >> 5, ks0 + steps);
    if (ks0 >= ks1) return;
    mm_core<0,0>(Abf, W, nullptr, P + (long)s*64*N, K, Kp, N, ks0, ks1, blockIdx.x);
}

// ============ output projection (single precision, bias) =============================
__global__ __launch_bounds__(256) void k_out_mm(
    const short* __restrict__ Abf, const float* __restrict__ W,
    const float* __restrict__ bias, float* __restrict__ y)
{
    mm_core<0,1>(Abf, W, bias, y, 1000, 1024, 50257, 0, 32, blockIdx.x);
}

// ============ GRU gates: sum split-K partials + biases ===============================
template<int LAYER>
__global__ void k_gates(const float* __restrict__ Pgi, const float* __restrict__ Pgh,
                        const float* __restrict__ h0,
                        const float* __restrict__ b_ih, const float* __restrict__ b_hh,
                        short* __restrict__ outhi, short* __restrict__ outlo,
                        float* __restrict__ ht, int SI, int SH)
{
    const int d = blockIdx.y;
    int i = blockIdx.x*256 + threadIdx.x;
    if (i >= 32000) return;
    int b = i / 500, q = i % 500;
    long base = (long)b*1500 + q;
    float g0 = b_ih[d*1500 + q], g1 = b_ih[d*1500 + 500 + q], g2 = b_ih[d*1500 + 1000 + q];
    for (int s = 0; s < SI; s++) {
        const float* P = Pgi + (long)(d*SI + s)*96000 + base;
        g0 += P[0]; g1 += P[500]; g2 += P[1000];
    }
    float h0v = b_hh[d*1500 + q], h1v = b_hh[d*1500 + 500 + q], h2v = b_hh[d*1500 + 1000 + q];
    for (int s = 0; s < SH; s++) {
        const float* P = Pgh + (long)(d*SH + s)*96000 + base;
        h0v += P[0]; h1v += P[500]; h2v += P[1000];
    }
    float hp = h0[((long)(LAYER*2 + d)*64 + b)*500 + q];
    float r = sigmoidf_(g0 + h0v);
    float z = sigmoidf_(g1 + h1v);
    float nn = tanhf(g2 + r*h2v);
    float o = (1.f - z)*nn + z*hp;
    long oo = (long)b*1024 + d*500 + q;
    short h = f2bf(o);
    outhi[oo] = h; outlo[oo] = f2bf(o - bf2f(h));
    if (LAYER == 1) ht[(long)b*1000 + d*500 + q] = o;
}

// ============ pt / window bounds (sums Wp partials) ===================================
__global__ void k_pt(const float* __restrict__ Pwp, const float* __restrict__ Wp_b,
                     const float* __restrict__ Vp_w, const float* __restrict__ Vp_b,
                     const int* __restrict__ lengths, int* __restrict__ p01, int S)
{
    int b = blockIdx.x;
    float ps = 0.f;
    for (int j = threadIdx.x; j < 1000; j += 256) {
        float v = Wp_b[j];
        for (int s = 0; s < S; s++) v += Pwp[(long)s*64000 + (long)b*1000 + j];
        ps += tanhf(v) * Vp_w[j];
    }
    for (int off = 32; off; off >>= 1) ps += __shfl_down(ps, off);
    __shared__ float red[4];
    int lane = threadIdx.x & 63, wave = threadIdx.x >> 6;
    if (lane == 0) red[wave] = ps;
    __syncthreads();
    if (threadIdx.x == 0) {
        float tot = red[0] + red[1] + red[2] + red[3];
        float s = 1.f/(1.f + expf(-(tot + Vp_b[0])));
        int len = lengths[b];
        int pt = (int)((float)len * s);
        int P0 = min(len - 5, max(0, pt - 5));
        int P1 = min(len, pt + 6);
        p01[2*b] = P0; p01[2*b+1] = P1;
    }
}

// ============ windowed attention; writes catbf [64][2048] bf16 ========================
__global__ void k_attn(const float* __restrict__ enc, const float* __restrict__ ht,
                       const int* __restrict__ p01, short* __restrict__ catbf)
{
    int b = blockIdx.x;
    __shared__ float hts[1000];
    __shared__ float hs[11][1000];
    __shared__ float aa[16];
    int p0 = p01[2*b], p1 = p01[2*b+1];
    for (int h = threadIdx.x; h < 1000; h += 256) hts[h] = ht[b*1000 + h];
    for (int k = 0; k < 11; k++) {
        int row = min(p0 + k, 1023);
        const float* er = enc + ((long)b*1024 + row)*1000;
        for (int h = threadIdx.x; h < 1000; h += 256) hs[k][h] = er[h];
    }
    __syncthreads();
    int lane = threadIdx.x & 63, wave = threadIdx.x >> 6;
    for (int k = wave; k < 11; k += 4) {
        float ps = 0.f;
        for (int h = lane; h < 1000; h += 64) ps += hts[h]*hs[k][h];
        for (int off = 32; off; off >>= 1) ps += __shfl_down(ps, off);
        if (lane == 0) aa[k] = ps;
    }
    __syncthreads();
    if (threadIdx.x == 0) {
        int nv = min(p1 - p0, 11);
        float m = -1e30f;
        for (int k = 0; k < nv; k++) m = fmaxf(m, aa[k]);
        float ssum = 0.f;
        for (int k = 0; k < 11; k++) { float e = (k < nv) ? expf(aa[k]-m) : 0.f; aa[k] = e; ssum += e; }
        float inv = 1.f/ssum;
        for (int k = 0; k < 11; k++) aa[k] *= inv;
    }
    __syncthreads();
    for (int h = threadIdx.x; h < 1000; h += 256) {
        float c = 0.f;
#pragma unroll
        for (int k = 0; k < 11; k++) c += aa[k]*hs[k][h];
        catbf[(long)b*2048 + h]        = f2bf(c);
        catbf[(long)b*2048 + 1000 + h] = f2bf(hts[h]);
    }
}

// ============ combine Wc partials + tanh -> habf bf16 =================================
__global__ void k_hattn(const float* __restrict__ Pwc, const float* __restrict__ Wc_b,
                        short* __restrict__ habf, int S)
{
    int i = blockIdx.x*256 + threadIdx.x;
    if (i >= 64000) return;
    int b = i / 1000, nn = i % 1000;
    float v = Wc_b[nn];
    for (int s = 0; s < S; s++) v += Pwc[(long)s*64000 + i];
    habf[(long)b*1024 + nn] = f2bf(tanhf(v));
}

// ============ log_softmax =============================================================
__global__ void k_lse_part(const float* __restrict__ y, float* __restrict__ part)
{
    const int V = 50257;
    int b = blockIdx.x >> 3, p = blockIdx.x & 7;
    const int Vc = (V + 7)/8;
    int start = p*Vc, end = min(V, start + Vc);
    float m = -1e30f, s = 0.f;
    for (int j = start + threadIdx.x; j < end; j += 256) {
        float v = y[(long)b*V + j];
        if (v > m) { s = s*expf(m - v) + 1.f; m = v; }
        else       { s += expf(v - m); }
    }
    __shared__ float ms[256], ss[256];
    ms[threadIdx.x] = m; ss[threadIdx.x] = s;
    __syncthreads();
    for (int st = 128; st; st >>= 1) {
        if (threadIdx.x < st) {
            float m1 = ms[threadIdx.x], s1 = ss[threadIdx.x];
            float m2 = ms[threadIdx.x+st], s2 = ss[threadIdx.x+st];
            float M = fmaxf(m1, m2);
            ms[threadIdx.x] = M;
            ss[threadIdx.x] = s1*expf(m1-M) + s2*expf(m2-M);
        }
        __syncthreads();
    }
    if (threadIdx.x == 0) { part[2*blockIdx.x] = ms[0]; part[2*blockIdx.x+1] = ss[0]; }
}

__global__ void k_lse_merge(const float* __restrict__ part, float* __restrict__ lse)
{
    int b = threadIdx.x;
    if (b >= 64) return;
    float M = -1e30f, S = 0.f;
    for (int p = 0; p < 8; p++) {
        float m2 = part[2*(b*8+p)], s2 = part[2*(b*8+p)+1];
        float Mn = fmaxf(M, m2);
        S = S*expf(M - Mn) + s2*expf(m2 - Mn);
        M = Mn;
    }
    lse[b] = M + logf(S);
}

__global__ void k_sub(float* __restrict__ y, const float* __restrict__ lse)
{
    const int V = 50257;
    int b = blockIdx.y;
    int j = blockIdx.x*256 + threadIdx.x;
    if (j < V) y[(long)b*V + j] -= lse[b];
}

// =====================================================================================
extern "C" void kernel_launch(void* const* d_in, const int* in_sizes, int n_in,
                              void* d_out, int out_size, void* d_ws, size_t ws_size,
                              hipStream_t stream)
{
    const int*   dec_in  = (const int*)  d_in[0];
    const float* attn_h  = (const float*)d_in[1];
    const float* enc     = (const float*)d_in[2];
    // d_in[3] = mask0 (unused: m_w == valid within the window)
    const int*   lengths = (const int*)  d_in[4];
    const float* h0      = (const float*)d_in[5];
    const float* embed   = (const float*)d_in[6];
    const float* w_ih0   = (const float*)d_in[7];
    const float* w_hh0   = (const float*)d_in[8];
    const float* b_ih0   = (const float*)d_in[9];
    const float* b_hh0   = (const float*)d_in[10];
    const float* w_ih1   = (const float*)d_in[11];
    const float* w_hh1   = (const float*)d_in[12];
    const float* b_ih1   = (const float*)d_in[13];
    const float* b_hh1   = (const float*)d_in[14];
    const float* Wp_w    = (const float*)d_in[15];
    const float* Wp_b    = (const float*)d_in[16];
    const float* Vp_w    = (const float*)d_in[17];
    const float* Vp_b    = (const float*)d_in[18];
    const float* Wc_w    = (const float*)d_in[19];
    const float* Wc_b    = (const float*)d_in[20];
    const float* out_w   = (const float*)d_in[21];
    const float* out_b   = (const float*)d_in[22];
    float* y = (float*)d_out;

    // ---- workspace layout, FLOAT units; sizes = ceil(shorts/2) + slack; NO overlaps ----
    float* ws = (float*)d_ws;
    short* xhi   = (short*)(ws + 0);        // 64*1312 sh = 41,984 fl -> 42,000
    short* xlo   = (short*)(ws + 42000);    // 42,000
    short* h0hi  = (short*)(ws + 84000);    // 4*64*512 sh = 65,536 fl -> 65,600
    short* h0lo  = (short*)(ws + 149600);   // 65,600
    short* x1hi  = (short*)(ws + 215200);   // 64*1024 sh = 32,768 fl -> 32,800
    short* x1lo  = (short*)(ws + 248000);   // 32,800
    short* hthi  = (short*)(ws + 280800);   // 32,800
    short* htlo  = (short*)(ws + 313600);   // 32,800
    short* catbf = (short*)(ws + 346400);   // 64*2048 sh = 65,536 fl -> 65,600
    short* habf  = (short*)(ws + 412000);   // 64*1024 sh = 32,768 fl -> 32,800
    float* ht    = ws + 444800;             // 64,000
    float* Pgi   = ws + 508800;             // 2*5*96000 = 960,000
    float* Pgh   = ws + 1468800;            // 2*2*96000 = 384,000
    float* Pwp   = ws + 1852800;            // 8*64,000 = 512,000
    float* Pwc   = ws + 2364800;            // 8*64,000 = 512,000
    float* part  = ws + 2876800;            // 1,024
    float* lse   = ws + 2877824;            // 64
    int*   p01   = (int*)(ws + 2877888);    // 128
    // total ~2.88M floats = 11.5 MB

    dim3 B256(256);

    k_prep<<<dim3((64*1312 + 4*64*512 + 1536 + 1536 + 3072 + 255)/256), B256, 0, stream>>>(
        dec_in, attn_h, embed, h0, xhi, xlo, h0hi, h0lo, x1hi, x1lo, hthi, htlo, habf, catbf);

    // GRU layer 0: ih K=1300 Kp=1312 (41 steps, S=5x9), hh K=500 Kp=512 (16 steps, S=2x8)
    k_gru_mm<0><<<dim3(24, 5, 4), B256, 0, stream>>>(
        xhi, xlo, h0hi, h0lo, w_ih0, w_hh0, Pgi, Pgh, 1300, 1312, 5, 9, 2, 8);
    k_gates<0><<<dim3(125, 2), B256, 0, stream>>>(Pgi, Pgh, h0, b_ih0, b_hh0, x1hi, x1lo, ht, 5, 2);

    // GRU layer 1: ih K=1000 Kp=1024 (32 steps, S=4x8)
    k_gru_mm<1><<<dim3(24, 4, 4), B256, 0, stream>>>(
        x1hi, x1lo, h0hi, h0lo, w_ih1, w_hh1, Pgi, Pgh, 1000, 1024, 4, 8, 2, 8);
    k_gates<1><<<dim3(125, 2), B256, 0, stream>>>(Pgi, Pgh, h0, b_ih1, b_hh1, hthi, htlo, ht, 4, 2);

    // predictive window: Wp (NN, K=1000 Kp=1024, split-precision)
    k_nn_split4<<<dim3(16, 8), B256, 0, stream>>>(hthi, htlo, Wp_w, Pwp, 1000, 1024, 1000, 4);
    k_pt<<<dim3(64), B256, 0, stream>>>(Pwp, Wp_b, Vp_w, Vp_b, lengths, p01, 8);

    // local attention -> catbf; Wc (NN, K=2000 Kp=2048, single bf16)
    k_attn<<<dim3(64), B256, 0, stream>>>(enc, ht, p01, catbf);
    k_nn_split<<<dim3(16, 8), B256, 0, stream>>>(catbf, Wc_w, Pwc, 2000, 2048, 1000, 8);
    k_hattn<<<dim3(250), B256, 0, stream>>>(Pwc, Wc_b, habf, 8);

    // output projection [64,50257]
    k_out_mm<<<dim3(786), B256, 0, stream>>>(habf, out_w, out_b, y);

    // log_softmax in place
    k_lse_part<<<dim3(512), B256, 0, stream>>>(y, part);
    k_lse_merge<<<dim3(1), dim3(64), 0, stream>>>(part, lse);
    k_sub<<<dim3(197, 64), B256, 0, stream>>>(y, lse);
}